// Round 4
// baseline (5215.878 us; speedup 1.0000x reference)
//
#include <hip/hip_runtime.h>

#define N_USERS 100000
#define N_ITEMS 50000
#define N_NODES 150000
#define EMBED_DIM 64
#define N_EDGES 4800000
#define N_LAYERS 3

#define BKT_SHIFT 7                                     // 128 rows / bucket
#define BKT_ROWS (1 << BKT_SHIFT)
#define N_BKT ((N_NODES + BKT_ROWS - 1) >> BKT_SHIFT)   // 1172
#define EPB 8192                                        // edges per block (hist/part)
#define NPB ((N_EDGES + EPB - 1) / EPB)                 // 586

// ---------- bf16 helpers (RNE, bit-exact, no type headaches) ----------
__device__ __forceinline__ unsigned short f2bf(float f) {
    unsigned u = __float_as_uint(f);
    u += 0x7fffu + ((u >> 16) & 1u);
    return (unsigned short)(u >> 16);
}
__device__ __forceinline__ float bf2f(unsigned short h) {
    return __uint_as_float((unsigned)h << 16);
}

// ---------------- init: acc = emb (f32), cur0 = bf16(emb) ----------------
__global__ void lgcn_init2(const float* __restrict__ user_emb,
                           const float* __restrict__ item_emb,
                           unsigned short* __restrict__ curb,
                           float* __restrict__ acc) {
    int i = blockIdx.x * blockDim.x + threadIdx.x;
    const int total = N_NODES * EMBED_DIM / 4;
    if (i >= total) return;
    const int user_elems = N_USERS * EMBED_DIM / 4;
    float4 v;
    if (i < user_elems) v = ((const float4*)user_emb)[i];
    else                v = ((const float4*)item_emb)[i - user_elems];
    ((float4*)acc)[i] = v;
    ushort4 o;
    o.x = f2bf(v.x); o.y = f2bf(v.y); o.z = f2bf(v.z); o.w = f2bf(v.w);
    ((ushort4*)curb)[i] = o;
}

// ---------------- bucket histogram ----------------
__global__ __launch_bounds__(256)
void k_hist(const int* __restrict__ row, int* __restrict__ bkt_cnt) {
    __shared__ int h[N_BKT];
    for (int i = threadIdx.x; i < N_BKT; i += 256) h[i] = 0;
    __syncthreads();
    int e0 = blockIdx.x * EPB;
    int e1 = e0 + EPB; if (e1 > N_EDGES) e1 = N_EDGES;
    for (int e = e0 + threadIdx.x; e < e1; e += 256)
        atomicAdd(&h[row[e] >> BKT_SHIFT], 1);
    __syncthreads();
    for (int i = threadIdx.x; i < N_BKT; i += 256)
        if (h[i]) atomicAdd(&bkt_cnt[i], h[i]);
}

// ---------------- scan of 1172 bucket counts ----------------
__global__ void k_scan(const int* __restrict__ bkt_cnt,
                       int* __restrict__ bkt_base,
                       int* __restrict__ bkt_cur) {
    __shared__ int sm[N_BKT];
    for (int i = threadIdx.x; i < N_BKT; i += blockDim.x) sm[i] = bkt_cnt[i];
    __syncthreads();
    if (threadIdx.x == 0) {
        int run = 0;
        for (int b = 0; b < N_BKT; ++b) { int t = sm[b]; sm[b] = run; run += t; }
    }
    __syncthreads();
    for (int i = threadIdx.x; i < N_BKT; i += blockDim.x) {
        bkt_base[i] = sm[i];
        bkt_cur[i]  = sm[i];
    }
    if (threadIdx.x == 0) bkt_base[N_BKT] = N_EDGES;
}

// ---------------- single-pass partition into bucket segments ----------------
// packed edge: meta = (col << 7) | row_local, val bits alongside (int2)
__global__ __launch_bounds__(256)
void k_part(const int* __restrict__ row,
            const int* __restrict__ col,
            const int* __restrict__ valI,
            int* __restrict__ bkt_cur,
            int2* __restrict__ edges) {
    __shared__ int h[N_BKT];
    __shared__ int off[N_BKT];
    int e0 = blockIdx.x * EPB;
    int e1 = e0 + EPB; if (e1 > N_EDGES) e1 = N_EDGES;
    for (int i = threadIdx.x; i < N_BKT; i += 256) h[i] = 0;
    __syncthreads();
    for (int e = e0 + threadIdx.x; e < e1; e += 256)
        atomicAdd(&h[row[e] >> BKT_SHIFT], 1);
    __syncthreads();
    for (int i = threadIdx.x; i < N_BKT; i += 256)
        if (h[i]) off[i] = atomicAdd(&bkt_cur[i], h[i]);
    __syncthreads();
    for (int e = e0 + threadIdx.x; e < e1; e += 256) {
        int r = row[e];
        int b = r >> BKT_SHIFT;
        int p = atomicAdd(&off[b], 1);
        edges[p] = make_int2((col[e] << BKT_SHIFT) | (r & (BKT_ROWS - 1)), valI[e]);
    }
}

// ---------------- SpMM with LDS accumulation, fused acc update ----------------
// one block per 128-row bucket; 32KB LDS f32 accumulator; edges order-free.
__global__ __launch_bounds__(256)
void lgcn_spmm_lds(const int* __restrict__ bkt_base,
                   const int2* __restrict__ edges,
                   const unsigned short* __restrict__ x,   // bf16 [N_NODES][64]
                   unsigned short* __restrict__ nxt,       // bf16 [N_NODES][64]
                   float* __restrict__ acc,
                   float s, int write_nxt) {
    __shared__ float sm[BKT_ROWS * EMBED_DIM];              // 32 KB
    float4* smf4 = (float4*)sm;
    for (int i = threadIdx.x; i < BKT_ROWS * EMBED_DIM / 4; i += 256)
        smf4[i] = make_float4(0.f, 0.f, 0.f, 0.f);
    __syncthreads();

    int b = blockIdx.x;
    int seg0 = bkt_base[b];
    int seg1 = bkt_base[b + 1];
    int wid  = threadIdx.x >> 6;
    int lane = threadIdx.x & 63;

    int cnt  = seg1 - seg0;
    int mend = seg0 + (cnt & ~15);          // 4 waves x 4-edge chunks
    for (int base = seg0 + wid * 4; base < mend; base += 16) {
        int2 e0 = edges[base + 0];
        int2 e1 = edges[base + 1];
        int2 e2 = edges[base + 2];
        int2 e3 = edges[base + 3];
        float x0 = bf2f(x[((size_t)(e0.x >> BKT_SHIFT) << 6) + lane]);
        float x1 = bf2f(x[((size_t)(e1.x >> BKT_SHIFT) << 6) + lane]);
        float x2 = bf2f(x[((size_t)(e2.x >> BKT_SHIFT) << 6) + lane]);
        float x3 = bf2f(x[((size_t)(e3.x >> BKT_SHIFT) << 6) + lane]);
        atomicAdd(&sm[((e0.x & (BKT_ROWS - 1)) << 6) + lane], __int_as_float(e0.y) * x0);
        atomicAdd(&sm[((e1.x & (BKT_ROWS - 1)) << 6) + lane], __int_as_float(e1.y) * x1);
        atomicAdd(&sm[((e2.x & (BKT_ROWS - 1)) << 6) + lane], __int_as_float(e2.y) * x2);
        atomicAdd(&sm[((e3.x & (BKT_ROWS - 1)) << 6) + lane], __int_as_float(e3.y) * x3);
    }
    for (int e = mend + wid; e < seg1; e += 4) {
        int2 ee = edges[e];
        float xv = bf2f(x[((size_t)(ee.x >> BKT_SHIFT) << 6) + lane]);
        atomicAdd(&sm[((ee.x & (BKT_ROWS - 1)) << 6) + lane], __int_as_float(ee.y) * xv);
    }
    __syncthreads();

    // writeback: acc = (acc + v)*s ; nxt = bf16(v)
    int row0 = b << BKT_SHIFT;
    int nrows = N_NODES - row0; if (nrows > BKT_ROWS) nrows = BKT_ROWS;
    int total4 = nrows * EMBED_DIM / 4;
    float4*  accf4 = (float4*)(acc + ((size_t)row0 << 6));
    ushort4* nxtf4 = (ushort4*)(nxt + ((size_t)row0 << 6));
    for (int i = threadIdx.x; i < total4; i += 256) {
        float4 v = smf4[i];
        float4 a = accf4[i];
        a.x = (a.x + v.x) * s; a.y = (a.y + v.y) * s;
        a.z = (a.z + v.z) * s; a.w = (a.w + v.w) * s;
        accf4[i] = a;
        if (write_nxt) {
            ushort4 o;
            o.x = f2bf(v.x); o.y = f2bf(v.y); o.z = f2bf(v.z); o.w = f2bf(v.w);
            nxtf4[i] = o;
        }
    }
}

// ---------------- fallback (atomic scatter, f32) ----------------
__global__ void lgcn_init(const float* __restrict__ user_emb,
                          const float* __restrict__ item_emb,
                          float* __restrict__ cur,
                          float* __restrict__ acc) {
    int i = blockIdx.x * blockDim.x + threadIdx.x;
    const int total = N_NODES * EMBED_DIM / 4;
    if (i >= total) return;
    const int user_elems = N_USERS * EMBED_DIM / 4;
    float4 v;
    if (i < user_elems) v = ((const float4*)user_emb)[i];
    else                v = ((const float4*)item_emb)[i - user_elems];
    ((float4*)cur)[i] = v;
    ((float4*)acc)[i] = v;
}

__global__ void lgcn_spmm_atomic(const int* __restrict__ row,
                                 const int* __restrict__ col,
                                 const float* __restrict__ val,
                                 const float* __restrict__ x,
                                 float* __restrict__ y) {
    long long t = (long long)blockIdx.x * blockDim.x + threadIdx.x;
    int e = (int)(t >> 6);
    int d = (int)(t & 63);
    if (e >= N_EDGES) return;
    atomicAdd(&y[(long long)row[e] * EMBED_DIM + d],
              val[e] * x[(long long)col[e] * EMBED_DIM + d]);
}

__global__ void lgcn_accum(const float* __restrict__ cur,
                           float* __restrict__ acc, float s) {
    int i = blockIdx.x * blockDim.x + threadIdx.x;
    const int total = N_NODES * EMBED_DIM / 4;
    if (i >= total) return;
    float4 a = ((const float4*)acc)[i];
    float4 c = ((const float4*)cur)[i];
    a.x = (a.x + c.x) * s; a.y = (a.y + c.y) * s;
    a.z = (a.z + c.z) * s; a.w = (a.w + c.w) * s;
    ((float4*)acc)[i] = a;
}

extern "C" void kernel_launch(void* const* d_in, const int* in_sizes, int n_in,
                              void* d_out, int out_size, void* d_ws, size_t ws_size,
                              hipStream_t stream) {
    const int*   adj_row  = (const int*)d_in[0];
    const int*   adj_col  = (const int*)d_in[1];
    const float* adj_val  = (const float*)d_in[2];
    const int*   adj_valI = (const int*)d_in[2];
    const float* user_emb = (const float*)d_in[3];
    const float* item_emb = (const float*)d_in[4];
    float* acc = (float*)d_out;

    const size_t buf_elems = (size_t)N_NODES * EMBED_DIM;

    // ---- workspace layout ----
    char* wp = (char*)d_ws;
    int* bkt_cnt  = (int*)wp;  wp += (size_t)N_BKT * sizeof(int);
    int* bkt_base = (int*)wp;  wp += (size_t)(N_BKT + 1) * sizeof(int);
    int* bkt_cur  = (int*)wp;  wp += (size_t)N_BKT * sizeof(int);
    wp = (char*)(((size_t)wp + 15) & ~(size_t)15);
    int2* edges   = (int2*)wp; wp += (size_t)N_EDGES * sizeof(int2);
    wp = (char*)(((size_t)wp + 15) & ~(size_t)15);
    unsigned short* curb = (unsigned short*)wp; wp += buf_elems * sizeof(unsigned short);
    unsigned short* nxtb = (unsigned short*)wp; wp += buf_elems * sizeof(unsigned short);
    size_t needed = (size_t)(wp - (char*)d_ws);

    if (needed <= ws_size) {
        // ---- bucket partition build ----
        hipMemsetAsync(bkt_cnt, 0, N_BKT * sizeof(int), stream);
        k_hist<<<NPB, 256, 0, stream>>>(adj_row, bkt_cnt);
        k_scan<<<1, 1024, 0, stream>>>(bkt_cnt, bkt_base, bkt_cur);
        k_part<<<NPB, 256, 0, stream>>>(adj_row, adj_col, adj_valI, bkt_cur, edges);

        // ---- init acc (f32) + cur0 (bf16) ----
        {
            const int total = N_NODES * EMBED_DIM / 4;
            lgcn_init2<<<(total + 255) / 256, 256, 0, stream>>>(user_emb, item_emb, curb, acc);
        }

        // ---- 3 LDS-accumulated SpMM layers ----
        unsigned short* a = curb;
        unsigned short* b = nxtb;
        for (int layer = 0; layer < N_LAYERS; ++layer) {
            float s = (layer == N_LAYERS - 1) ? (1.0f / (N_LAYERS + 1)) : 1.0f;
            int write_nxt = (layer != N_LAYERS - 1);
            lgcn_spmm_lds<<<N_BKT, 256, 0, stream>>>(bkt_base, edges, a, b, acc, s, write_nxt);
            unsigned short* t = a; a = b; b = t;
        }
    } else {
        // ---- fallback: atomic path (f32) ----
        float* curF = (float*)d_ws;
        float* nxtF = curF + buf_elems;
        const int total = N_NODES * EMBED_DIM / 4;
        lgcn_init<<<(total + 255) / 256, 256, 0, stream>>>(user_emb, item_emb, curF, acc);
        float* a = curF; float* b = nxtF;
        for (int layer = 0; layer < N_LAYERS; ++layer) {
            hipMemsetAsync(b, 0, buf_elems * sizeof(float), stream);
            long long tthr = (long long)N_EDGES * 64;
            lgcn_spmm_atomic<<<(unsigned)((tthr + 255) / 256), 256, 0, stream>>>(
                adj_row, adj_col, adj_val, a, b);
            float s = (layer == N_LAYERS - 1) ? (1.0f / (N_LAYERS + 1)) : 1.0f;
            lgcn_accum<<<(total + 255) / 256, 256, 0, stream>>>(b, acc, s);
            float* t = a; a = b; b = t;
        }
    }
}

// Round 5
// 675.130 us; speedup vs baseline: 7.7257x; 7.7257x over previous
//
#include <hip/hip_runtime.h>

#define N_USERS 100000
#define N_ITEMS 50000
#define N_NODES 150000
#define EMBED_DIM 64
#define N_EDGES 4800000
#define N_LAYERS 3

#define BKT_SHIFT 7                                     // 128 rows / bucket
#define BKT_ROWS (1 << BKT_SHIFT)
#define N_BKT ((N_NODES + BKT_ROWS - 1) >> BKT_SHIFT)   // 1172
#define EPB 8192                                        // edges per block (hist/part)
#define NPB ((N_EDGES + EPB - 1) / EPB)                 // 586

// ---------- bf16 helpers (RNE) ----------
__device__ __forceinline__ unsigned short f2bf(float f) {
    unsigned u = __float_as_uint(f);
    u += 0x7fffu + ((u >> 16) & 1u);
    return (unsigned short)(u >> 16);
}
__device__ __forceinline__ float bf2f(unsigned short h) {
    return __uint_as_float((unsigned)h << 16);
}

// ---------------- init: acc = emb (f32), cur0 = bf16(emb) ----------------
__global__ void lgcn_init2(const float* __restrict__ user_emb,
                           const float* __restrict__ item_emb,
                           unsigned short* __restrict__ curb,
                           float* __restrict__ acc) {
    int i = blockIdx.x * blockDim.x + threadIdx.x;
    const int total = N_NODES * EMBED_DIM / 4;
    if (i >= total) return;
    const int user_elems = N_USERS * EMBED_DIM / 4;
    float4 v;
    if (i < user_elems) v = ((const float4*)user_emb)[i];
    else                v = ((const float4*)item_emb)[i - user_elems];
    ((float4*)acc)[i] = v;
    ushort4 o;
    o.x = f2bf(v.x); o.y = f2bf(v.y); o.z = f2bf(v.z); o.w = f2bf(v.w);
    ((ushort4*)curb)[i] = o;
}

// ---------------- bucket histogram (LDS int atomics — native) ----------------
__global__ __launch_bounds__(256)
void k_hist(const int* __restrict__ row, int* __restrict__ bkt_cnt) {
    __shared__ int h[N_BKT];
    for (int i = threadIdx.x; i < N_BKT; i += 256) h[i] = 0;
    __syncthreads();
    int e0 = blockIdx.x * EPB;
    int e1 = e0 + EPB; if (e1 > N_EDGES) e1 = N_EDGES;
    for (int e = e0 + threadIdx.x; e < e1; e += 256)
        atomicAdd(&h[row[e] >> BKT_SHIFT], 1);
    __syncthreads();
    for (int i = threadIdx.x; i < N_BKT; i += 256)
        if (h[i]) atomicAdd(&bkt_cnt[i], h[i]);
}

// ---------------- scan of 1172 bucket counts ----------------
__global__ void k_scan(const int* __restrict__ bkt_cnt,
                       int* __restrict__ bkt_base,
                       int* __restrict__ bkt_cur) {
    __shared__ int sm[N_BKT];
    for (int i = threadIdx.x; i < N_BKT; i += blockDim.x) sm[i] = bkt_cnt[i];
    __syncthreads();
    if (threadIdx.x == 0) {
        int run = 0;
        for (int b = 0; b < N_BKT; ++b) { int t = sm[b]; sm[b] = run; run += t; }
    }
    __syncthreads();
    for (int i = threadIdx.x; i < N_BKT; i += blockDim.x) {
        bkt_base[i] = sm[i];
        bkt_cur[i]  = sm[i];
    }
    if (threadIdx.x == 0) bkt_base[N_BKT] = N_EDGES;
}

// ---------------- single-pass partition into bucket segments ----------------
// packed edge: meta = (col << 7) | row_local, val bits alongside (int2)
__global__ __launch_bounds__(256)
void k_part(const int* __restrict__ row,
            const int* __restrict__ col,
            const int* __restrict__ valI,
            int* __restrict__ bkt_cur,
            int2* __restrict__ edges) {
    __shared__ int h[N_BKT];
    __shared__ int off[N_BKT];
    int e0 = blockIdx.x * EPB;
    int e1 = e0 + EPB; if (e1 > N_EDGES) e1 = N_EDGES;
    for (int i = threadIdx.x; i < N_BKT; i += 256) h[i] = 0;
    __syncthreads();
    for (int e = e0 + threadIdx.x; e < e1; e += 256)
        atomicAdd(&h[row[e] >> BKT_SHIFT], 1);
    __syncthreads();
    for (int i = threadIdx.x; i < N_BKT; i += 256)
        if (h[i]) off[i] = atomicAdd(&bkt_cur[i], h[i]);
    __syncthreads();
    for (int e = e0 + threadIdx.x; e < e1; e += 256) {
        int r = row[e];
        int b = r >> BKT_SHIFT;
        int p = atomicAdd(&off[b], 1);
        edges[p] = make_int2((col[e] << BKT_SHIFT) | (r & (BKT_ROWS - 1)), valI[e]);
    }
}

// ---------------- per-bucket counting sort -> row-sorted CSR + rowptr ------
// one block per bucket; output window is the bucket's contiguous ~32KB segment
// (L2-resident, line-filling). LDS atomics are int (native ds_add).
__global__ __launch_bounds__(256)
void k_sort(const int* __restrict__ bkt_base,
            const int2* __restrict__ edges,
            int2* __restrict__ csr,
            int* __restrict__ rowptr) {
    __shared__ int h[BKT_ROWS];
    __shared__ int off[BKT_ROWS];
    int b = blockIdx.x;
    int seg0 = bkt_base[b], seg1 = bkt_base[b + 1];
    if (threadIdx.x < BKT_ROWS) h[threadIdx.x] = 0;
    __syncthreads();
    for (int e = seg0 + threadIdx.x; e < seg1; e += 256)
        atomicAdd(&h[edges[e].x & (BKT_ROWS - 1)], 1);
    __syncthreads();
    if (threadIdx.x == 0) {
        int run = 0;
        for (int i = 0; i < BKT_ROWS; ++i) { int t = h[i]; h[i] = run; run += t; }
    }
    __syncthreads();
    if (threadIdx.x < BKT_ROWS) off[threadIdx.x] = h[threadIdx.x];
    __syncthreads();
    for (int e = seg0 + threadIdx.x; e < seg1; e += 256) {
        int2 ee = edges[e];
        int rl = ee.x & (BKT_ROWS - 1);
        int p = atomicAdd(&off[rl], 1);
        csr[seg0 + p] = make_int2(ee.x >> BKT_SHIFT, ee.y);   // (col, val bits)
    }
    int row0 = b << BKT_SHIFT;
    int nrows = N_NODES - row0; if (nrows > BKT_ROWS) nrows = BKT_ROWS;
    if (threadIdx.x < nrows) rowptr[row0 + threadIdx.x] = seg0 + h[threadIdx.x];
    if (b == N_BKT - 1 && threadIdx.x == 0) rowptr[N_NODES] = N_EDGES;
}

// ---------------- gather SpMV (bf16 x), fused acc update ----------------
__global__ __launch_bounds__(256)
void lgcn_spmv_b(const int* __restrict__ rowptr,
                 const int2* __restrict__ cv,
                 const unsigned short* __restrict__ x,   // bf16 [N_NODES][64]
                 unsigned short* __restrict__ nxt,       // bf16 [N_NODES][64]
                 float* __restrict__ acc,
                 float s, int write_nxt) {
    int t = blockIdx.x * blockDim.x + threadIdx.x;
    int wave = t >> 6;
    int lane = t & 63;
    if (wave >= N_NODES) return;
    int r = __builtin_amdgcn_readfirstlane(wave);
    int start = rowptr[r];
    int end   = rowptr[r + 1];
    float s0 = 0.f, s1 = 0.f, s2 = 0.f, s3 = 0.f;
    int j = start;
    for (; j + 4 <= end; j += 4) {
        int2 a0 = cv[j], a1 = cv[j + 1], a2 = cv[j + 2], a3 = cv[j + 3];
        s0 += __int_as_float(a0.y) * bf2f(x[((size_t)a0.x << 6) + lane]);
        s1 += __int_as_float(a1.y) * bf2f(x[((size_t)a1.x << 6) + lane]);
        s2 += __int_as_float(a2.y) * bf2f(x[((size_t)a2.x << 6) + lane]);
        s3 += __int_as_float(a3.y) * bf2f(x[((size_t)a3.x << 6) + lane]);
    }
    for (; j < end; ++j) {
        int2 a = cv[j];
        s0 += __int_as_float(a.y) * bf2f(x[((size_t)a.x << 6) + lane]);
    }
    float sum = (s0 + s1) + (s2 + s3);
    size_t o = ((size_t)r << 6) + lane;
    if (write_nxt) nxt[o] = f2bf(sum);
    acc[o] = (acc[o] + sum) * s;
}

// ---------------- fallback (atomic scatter, f32) ----------------
__global__ void lgcn_init(const float* __restrict__ user_emb,
                          const float* __restrict__ item_emb,
                          float* __restrict__ cur,
                          float* __restrict__ acc) {
    int i = blockIdx.x * blockDim.x + threadIdx.x;
    const int total = N_NODES * EMBED_DIM / 4;
    if (i >= total) return;
    const int user_elems = N_USERS * EMBED_DIM / 4;
    float4 v;
    if (i < user_elems) v = ((const float4*)user_emb)[i];
    else                v = ((const float4*)item_emb)[i - user_elems];
    ((float4*)cur)[i] = v;
    ((float4*)acc)[i] = v;
}

__global__ void lgcn_spmm_atomic(const int* __restrict__ row,
                                 const int* __restrict__ col,
                                 const float* __restrict__ val,
                                 const float* __restrict__ x,
                                 float* __restrict__ y) {
    long long t = (long long)blockIdx.x * blockDim.x + threadIdx.x;
    int e = (int)(t >> 6);
    int d = (int)(t & 63);
    if (e >= N_EDGES) return;
    atomicAdd(&y[(long long)row[e] * EMBED_DIM + d],
              val[e] * x[(long long)col[e] * EMBED_DIM + d]);
}

__global__ void lgcn_accum(const float* __restrict__ cur,
                           float* __restrict__ acc, float s) {
    int i = blockIdx.x * blockDim.x + threadIdx.x;
    const int total = N_NODES * EMBED_DIM / 4;
    if (i >= total) return;
    float4 a = ((const float4*)acc)[i];
    float4 c = ((const float4*)cur)[i];
    a.x = (a.x + c.x) * s; a.y = (a.y + c.y) * s;
    a.z = (a.z + c.z) * s; a.w = (a.w + c.w) * s;
    ((float4*)acc)[i] = a;
}

extern "C" void kernel_launch(void* const* d_in, const int* in_sizes, int n_in,
                              void* d_out, int out_size, void* d_ws, size_t ws_size,
                              hipStream_t stream) {
    const int*   adj_row  = (const int*)d_in[0];
    const int*   adj_col  = (const int*)d_in[1];
    const float* adj_val  = (const float*)d_in[2];
    const int*   adj_valI = (const int*)d_in[2];
    const float* user_emb = (const float*)d_in[3];
    const float* item_emb = (const float*)d_in[4];
    float* acc = (float*)d_out;

    const size_t buf_elems = (size_t)N_NODES * EMBED_DIM;

    // ---- workspace layout ----
    char* wp = (char*)d_ws;
    int* bkt_cnt  = (int*)wp;  wp += (size_t)N_BKT * sizeof(int);
    int* bkt_base = (int*)wp;  wp += (size_t)(N_BKT + 1) * sizeof(int);
    int* bkt_cur  = (int*)wp;  wp += (size_t)N_BKT * sizeof(int);
    int* rowptr   = (int*)wp;  wp += (size_t)(N_NODES + 1) * sizeof(int);
    wp = (char*)(((size_t)wp + 15) & ~(size_t)15);
    int2* edges   = (int2*)wp; wp += (size_t)N_EDGES * sizeof(int2);
    wp = (char*)(((size_t)wp + 15) & ~(size_t)15);
    int2* csr_cv  = (int2*)wp; wp += (size_t)N_EDGES * sizeof(int2);
    wp = (char*)(((size_t)wp + 15) & ~(size_t)15);
    unsigned short* curb = (unsigned short*)wp; wp += buf_elems * sizeof(unsigned short);
    unsigned short* nxtb = (unsigned short*)wp; wp += buf_elems * sizeof(unsigned short);
    size_t needed = (size_t)(wp - (char*)d_ws);

    if (needed <= ws_size) {
        // ---- build: bucket partition + per-bucket counting sort ----
        hipMemsetAsync(bkt_cnt, 0, N_BKT * sizeof(int), stream);
        k_hist<<<NPB, 256, 0, stream>>>(adj_row, bkt_cnt);
        k_scan<<<1, 1024, 0, stream>>>(bkt_cnt, bkt_base, bkt_cur);
        k_part<<<NPB, 256, 0, stream>>>(adj_row, adj_col, adj_valI, bkt_cur, edges);
        k_sort<<<N_BKT, 256, 0, stream>>>(bkt_base, edges, csr_cv, rowptr);

        // ---- init acc (f32) + cur0 (bf16) ----
        {
            const int total = N_NODES * EMBED_DIM / 4;
            lgcn_init2<<<(total + 255) / 256, 256, 0, stream>>>(user_emb, item_emb, curb, acc);
        }

        // ---- 3 gather-SpMV layers (bf16 x, f32 accumulate) ----
        const long long tthreads = (long long)N_NODES * 64;
        const int nblk = (int)((tthreads + 255) / 256);
        unsigned short* a = curb;
        unsigned short* b = nxtb;
        for (int layer = 0; layer < N_LAYERS; ++layer) {
            float s = (layer == N_LAYERS - 1) ? (1.0f / (N_LAYERS + 1)) : 1.0f;
            int write_nxt = (layer != N_LAYERS - 1);
            lgcn_spmv_b<<<nblk, 256, 0, stream>>>(rowptr, csr_cv, a, b, acc, s, write_nxt);
            unsigned short* t = a; a = b; b = t;
        }
    } else {
        // ---- fallback: atomic path (f32) ----
        float* curF = (float*)d_ws;
        float* nxtF = curF + buf_elems;
        const int total = N_NODES * EMBED_DIM / 4;
        lgcn_init<<<(total + 255) / 256, 256, 0, stream>>>(user_emb, item_emb, curF, acc);
        float* a = curF; float* b = nxtF;
        for (int layer = 0; layer < N_LAYERS; ++layer) {
            hipMemsetAsync(b, 0, buf_elems * sizeof(float), stream);
            long long tthr = (long long)N_EDGES * 64;
            lgcn_spmm_atomic<<<(unsigned)((tthr + 255) / 256), 256, 0, stream>>>(
                adj_row, adj_col, adj_val, a, b);
            float s = (layer == N_LAYERS - 1) ? (1.0f / (N_LAYERS + 1)) : 1.0f;
            lgcn_accum<<<(total + 255) / 256, 256, 0, stream>>>(b, acc, s);
            float* t = a; a = b; b = t;
        }
    }
}

// Round 6
// 657.050 us; speedup vs baseline: 7.9383x; 1.0275x over previous
//
#include <hip/hip_runtime.h>

#define N_USERS 100000
#define N_ITEMS 50000
#define N_NODES 150000
#define EMBED_DIM 64
#define N_EDGES 4800000
#define N_LAYERS 3

#define BKT_SHIFT 7                                     // 128 rows / bucket
#define BKT_ROWS (1 << BKT_SHIFT)
#define N_BKT ((N_NODES + BKT_ROWS - 1) >> BKT_SHIFT)   // 1172
#define EPB 8192                                        // edges per block (hist/part)
#define NPB ((N_EDGES + EPB - 1) / EPB)                 // 586

// ---------- bf16 helpers (RNE) ----------
__device__ __forceinline__ unsigned short f2bf(float f) {
    unsigned u = __float_as_uint(f);
    u += 0x7fffu + ((u >> 16) & 1u);
    return (unsigned short)(u >> 16);
}
__device__ __forceinline__ float bf2f(unsigned short h) {
    return __uint_as_float((unsigned)h << 16);
}

// ---------------- init: acc = emb (f32), cur0 = bf16(emb) ----------------
__global__ void lgcn_init2(const float* __restrict__ user_emb,
                           const float* __restrict__ item_emb,
                           unsigned short* __restrict__ curb,
                           float* __restrict__ acc) {
    int i = blockIdx.x * blockDim.x + threadIdx.x;
    const int total = N_NODES * EMBED_DIM / 4;
    if (i >= total) return;
    const int user_elems = N_USERS * EMBED_DIM / 4;
    float4 v;
    if (i < user_elems) v = ((const float4*)user_emb)[i];
    else                v = ((const float4*)item_emb)[i - user_elems];
    ((float4*)acc)[i] = v;
    ushort4 o;
    o.x = f2bf(v.x); o.y = f2bf(v.y); o.z = f2bf(v.z); o.w = f2bf(v.w);
    ((ushort4*)curb)[i] = o;
}

// ---------------- bucket histogram ----------------
__global__ __launch_bounds__(256)
void k_hist(const int* __restrict__ row, int* __restrict__ bkt_cnt) {
    __shared__ int h[N_BKT];
    for (int i = threadIdx.x; i < N_BKT; i += 256) h[i] = 0;
    __syncthreads();
    int e0 = blockIdx.x * EPB;
    int e1 = e0 + EPB; if (e1 > N_EDGES) e1 = N_EDGES;
    for (int e = e0 + threadIdx.x; e < e1; e += 256)
        atomicAdd(&h[row[e] >> BKT_SHIFT], 1);
    __syncthreads();
    for (int i = threadIdx.x; i < N_BKT; i += 256)
        if (h[i]) atomicAdd(&bkt_cnt[i], h[i]);
}

// ---------------- scan of 1172 bucket counts (chunked parallel) ----------------
#define SCAN_T 256
#define SCAN_C ((N_BKT + SCAN_T - 1) / SCAN_T)   // 5
__global__ void k_scan(const int* __restrict__ bkt_cnt,
                       int* __restrict__ bkt_base,
                       int* __restrict__ bkt_cur) {
    __shared__ int part[SCAN_T];
    int t = threadIdx.x;
    int c0 = t * SCAN_C;
    int local[SCAN_C];
    int run = 0;
    for (int k = 0; k < SCAN_C; ++k) {
        int i = c0 + k;
        int v = (i < N_BKT) ? bkt_cnt[i] : 0;
        local[k] = run;
        run += v;
    }
    part[t] = run;
    __syncthreads();
    if (t == 0) {
        int r2 = 0;
        for (int i = 0; i < SCAN_T; ++i) { int v = part[i]; part[i] = r2; r2 += v; }
    }
    __syncthreads();
    int base = part[t];
    for (int k = 0; k < SCAN_C; ++k) {
        int i = c0 + k;
        if (i < N_BKT) {
            int v = base + local[k];
            bkt_base[i] = v;
            bkt_cur[i]  = v;
        }
    }
    if (t == 0) bkt_base[N_BKT] = N_EDGES;
}

// ---------------- single-pass partition into bucket segments ----------------
__global__ __launch_bounds__(256)
void k_part(const int* __restrict__ row,
            const int* __restrict__ col,
            const int* __restrict__ valI,
            int* __restrict__ bkt_cur,
            int2* __restrict__ edges) {
    __shared__ int h[N_BKT];
    __shared__ int off[N_BKT];
    int e0 = blockIdx.x * EPB;
    int e1 = e0 + EPB; if (e1 > N_EDGES) e1 = N_EDGES;
    for (int i = threadIdx.x; i < N_BKT; i += 256) h[i] = 0;
    __syncthreads();
    for (int e = e0 + threadIdx.x; e < e1; e += 256)
        atomicAdd(&h[row[e] >> BKT_SHIFT], 1);
    __syncthreads();
    for (int i = threadIdx.x; i < N_BKT; i += 256)
        if (h[i]) off[i] = atomicAdd(&bkt_cur[i], h[i]);
    __syncthreads();
    for (int e = e0 + threadIdx.x; e < e1; e += 256) {
        int r = row[e];
        int b = r >> BKT_SHIFT;
        int p = atomicAdd(&off[b], 1);
        edges[p] = make_int2((col[e] << BKT_SHIFT) | (r & (BKT_ROWS - 1)), valI[e]);
    }
}

// ---------------- per-bucket counting sort -> row-sorted CSR + rowptr ------
__global__ __launch_bounds__(256)
void k_sort(const int* __restrict__ bkt_base,
            const int2* __restrict__ edges,
            int2* __restrict__ csr,
            int* __restrict__ rowptr) {
    __shared__ int h[BKT_ROWS];
    __shared__ int off[BKT_ROWS];
    int b = blockIdx.x;
    int seg0 = bkt_base[b], seg1 = bkt_base[b + 1];
    if (threadIdx.x < BKT_ROWS) h[threadIdx.x] = 0;
    __syncthreads();
    for (int e = seg0 + threadIdx.x; e < seg1; e += 256)
        atomicAdd(&h[edges[e].x & (BKT_ROWS - 1)], 1);
    __syncthreads();
    if (threadIdx.x == 0) {
        int run = 0;
        for (int i = 0; i < BKT_ROWS; ++i) { int t = h[i]; h[i] = run; run += t; }
    }
    __syncthreads();
    if (threadIdx.x < BKT_ROWS) off[threadIdx.x] = h[threadIdx.x];
    __syncthreads();
    for (int e = seg0 + threadIdx.x; e < seg1; e += 256) {
        int2 ee = edges[e];
        int rl = ee.x & (BKT_ROWS - 1);
        int p = atomicAdd(&off[rl], 1);
        csr[seg0 + p] = make_int2(ee.x >> BKT_SHIFT, ee.y);   // (col, val bits)
    }
    int row0 = b << BKT_SHIFT;
    int nrows = N_NODES - row0; if (nrows > BKT_ROWS) nrows = BKT_ROWS;
    if (threadIdx.x < nrows) rowptr[row0 + threadIdx.x] = seg0 + h[threadIdx.x];
    if (b == N_BKT - 1 && threadIdx.x == 0) rowptr[N_NODES] = N_EDGES;
}

// ---------------- gather SpMV (bf16 x), 8-deep MLP, fused acc ----------------
__global__ __launch_bounds__(256)
void lgcn_spmv_b(const int* __restrict__ rowptr,
                 const int2* __restrict__ cv,
                 const unsigned short* __restrict__ x,   // bf16 [N_NODES][64]
                 unsigned short* __restrict__ nxt,       // bf16 [N_NODES][64]
                 float* __restrict__ acc,
                 float s, int write_nxt) {
    int t = blockIdx.x * blockDim.x + threadIdx.x;
    int wave = t >> 6;
    int lane = t & 63;
    if (wave >= N_NODES) return;
    int r = __builtin_amdgcn_readfirstlane(wave);
    int start = rowptr[r];
    int end   = rowptr[r + 1];
    float a0 = 0.f, a1 = 0.f, a2 = 0.f, a3 = 0.f;
    float a4 = 0.f, a5 = 0.f, a6 = 0.f, a7 = 0.f;
    int j = start;
    for (; j + 8 <= end; j += 8) {
        int2 e0 = cv[j + 0], e1 = cv[j + 1], e2 = cv[j + 2], e3 = cv[j + 3];
        int2 e4 = cv[j + 4], e5 = cv[j + 5], e6 = cv[j + 6], e7 = cv[j + 7];
        float x0 = bf2f(x[((size_t)e0.x << 6) + lane]);
        float x1 = bf2f(x[((size_t)e1.x << 6) + lane]);
        float x2 = bf2f(x[((size_t)e2.x << 6) + lane]);
        float x3 = bf2f(x[((size_t)e3.x << 6) + lane]);
        float x4 = bf2f(x[((size_t)e4.x << 6) + lane]);
        float x5 = bf2f(x[((size_t)e5.x << 6) + lane]);
        float x6 = bf2f(x[((size_t)e6.x << 6) + lane]);
        float x7 = bf2f(x[((size_t)e7.x << 6) + lane]);
        a0 += __int_as_float(e0.y) * x0;
        a1 += __int_as_float(e1.y) * x1;
        a2 += __int_as_float(e2.y) * x2;
        a3 += __int_as_float(e3.y) * x3;
        a4 += __int_as_float(e4.y) * x4;
        a5 += __int_as_float(e5.y) * x5;
        a6 += __int_as_float(e6.y) * x6;
        a7 += __int_as_float(e7.y) * x7;
    }
    if (j + 4 <= end) {
        int2 e0 = cv[j + 0], e1 = cv[j + 1], e2 = cv[j + 2], e3 = cv[j + 3];
        a0 += __int_as_float(e0.y) * bf2f(x[((size_t)e0.x << 6) + lane]);
        a1 += __int_as_float(e1.y) * bf2f(x[((size_t)e1.x << 6) + lane]);
        a2 += __int_as_float(e2.y) * bf2f(x[((size_t)e2.x << 6) + lane]);
        a3 += __int_as_float(e3.y) * bf2f(x[((size_t)e3.x << 6) + lane]);
        j += 4;
    }
    for (; j < end; ++j) {
        int2 e = cv[j];
        a0 += __int_as_float(e.y) * bf2f(x[((size_t)e.x << 6) + lane]);
    }
    float sum = ((a0 + a1) + (a2 + a3)) + ((a4 + a5) + (a6 + a7));
    size_t o = ((size_t)r << 6) + lane;
    if (write_nxt) nxt[o] = f2bf(sum);
    acc[o] = (acc[o] + sum) * s;
}

// ---------------- fallback (atomic scatter, f32) ----------------
__global__ void lgcn_init(const float* __restrict__ user_emb,
                          const float* __restrict__ item_emb,
                          float* __restrict__ cur,
                          float* __restrict__ acc) {
    int i = blockIdx.x * blockDim.x + threadIdx.x;
    const int total = N_NODES * EMBED_DIM / 4;
    if (i >= total) return;
    const int user_elems = N_USERS * EMBED_DIM / 4;
    float4 v;
    if (i < user_elems) v = ((const float4*)user_emb)[i];
    else                v = ((const float4*)item_emb)[i - user_elems];
    ((float4*)cur)[i] = v;
    ((float4*)acc)[i] = v;
}

__global__ void lgcn_spmm_atomic(const int* __restrict__ row,
                                 const int* __restrict__ col,
                                 const float* __restrict__ val,
                                 const float* __restrict__ x,
                                 float* __restrict__ y) {
    long long t = (long long)blockIdx.x * blockDim.x + threadIdx.x;
    int e = (int)(t >> 6);
    int d = (int)(t & 63);
    if (e >= N_EDGES) return;
    atomicAdd(&y[(long long)row[e] * EMBED_DIM + d],
              val[e] * x[(long long)col[e] * EMBED_DIM + d]);
}

__global__ void lgcn_accum(const float* __restrict__ cur,
                           float* __restrict__ acc, float s) {
    int i = blockIdx.x * blockDim.x + threadIdx.x;
    const int total = N_NODES * EMBED_DIM / 4;
    if (i >= total) return;
    float4 a = ((const float4*)acc)[i];
    float4 c = ((const float4*)cur)[i];
    a.x = (a.x + c.x) * s; a.y = (a.y + c.y) * s;
    a.z = (a.z + c.z) * s; a.w = (a.w + c.w) * s;
    ((float4*)acc)[i] = a;
}

extern "C" void kernel_launch(void* const* d_in, const int* in_sizes, int n_in,
                              void* d_out, int out_size, void* d_ws, size_t ws_size,
                              hipStream_t stream) {
    const int*   adj_row  = (const int*)d_in[0];
    const int*   adj_col  = (const int*)d_in[1];
    const float* adj_val  = (const float*)d_in[2];
    const int*   adj_valI = (const int*)d_in[2];
    const float* user_emb = (const float*)d_in[3];
    const float* item_emb = (const float*)d_in[4];
    float* acc = (float*)d_out;

    const size_t buf_elems = (size_t)N_NODES * EMBED_DIM;

    // ---- workspace layout ----
    char* wp = (char*)d_ws;
    int* bkt_cnt  = (int*)wp;  wp += (size_t)N_BKT * sizeof(int);
    int* bkt_base = (int*)wp;  wp += (size_t)(N_BKT + 1) * sizeof(int);
    int* bkt_cur  = (int*)wp;  wp += (size_t)N_BKT * sizeof(int);
    int* rowptr   = (int*)wp;  wp += (size_t)(N_NODES + 1) * sizeof(int);
    wp = (char*)(((size_t)wp + 15) & ~(size_t)15);
    int2* edges   = (int2*)wp; wp += (size_t)N_EDGES * sizeof(int2);
    wp = (char*)(((size_t)wp + 15) & ~(size_t)15);
    int2* csr_cv  = (int2*)wp; wp += (size_t)N_EDGES * sizeof(int2);
    wp = (char*)(((size_t)wp + 15) & ~(size_t)15);
    unsigned short* curb = (unsigned short*)wp; wp += buf_elems * sizeof(unsigned short);
    unsigned short* nxtb = (unsigned short*)wp; wp += buf_elems * sizeof(unsigned short);
    size_t needed = (size_t)(wp - (char*)d_ws);

    if (needed <= ws_size) {
        // ---- build: bucket partition + per-bucket counting sort ----
        hipMemsetAsync(bkt_cnt, 0, N_BKT * sizeof(int), stream);
        k_hist<<<NPB, 256, 0, stream>>>(adj_row, bkt_cnt);
        k_scan<<<1, SCAN_T, 0, stream>>>(bkt_cnt, bkt_base, bkt_cur);
        k_part<<<NPB, 256, 0, stream>>>(adj_row, adj_col, adj_valI, bkt_cur, edges);
        k_sort<<<N_BKT, 256, 0, stream>>>(bkt_base, edges, csr_cv, rowptr);

        // ---- init acc (f32) + cur0 (bf16) ----
        {
            const int total = N_NODES * EMBED_DIM / 4;
            lgcn_init2<<<(total + 255) / 256, 256, 0, stream>>>(user_emb, item_emb, curb, acc);
        }

        // ---- 3 gather-SpMV layers (bf16 x, f32 accumulate) ----
        const long long tthreads = (long long)N_NODES * 64;
        const int nblk = (int)((tthreads + 255) / 256);
        unsigned short* a = curb;
        unsigned short* b = nxtb;
        for (int layer = 0; layer < N_LAYERS; ++layer) {
            float s = (layer == N_LAYERS - 1) ? (1.0f / (N_LAYERS + 1)) : 1.0f;
            int write_nxt = (layer != N_LAYERS - 1);
            lgcn_spmv_b<<<nblk, 256, 0, stream>>>(rowptr, csr_cv, a, b, acc, s, write_nxt);
            unsigned short* t = a; a = b; b = t;
        }
    } else {
        // ---- fallback: atomic path (f32) ----
        float* curF = (float*)d_ws;
        float* nxtF = curF + buf_elems;
        const int total = N_NODES * EMBED_DIM / 4;
        lgcn_init<<<(total + 255) / 256, 256, 0, stream>>>(user_emb, item_emb, curF, acc);
        float* a = curF; float* b = nxtF;
        for (int layer = 0; layer < N_LAYERS; ++layer) {
            hipMemsetAsync(b, 0, buf_elems * sizeof(float), stream);
            long long tthr = (long long)N_EDGES * 64;
            lgcn_spmm_atomic<<<(unsigned)((tthr + 255) / 256), 256, 0, stream>>>(
                adj_row, adj_col, adj_val, a, b);
            float s = (layer == N_LAYERS - 1) ? (1.0f / (N_LAYERS + 1)) : 1.0f;
            lgcn_accum<<<(total + 255) / 256, 256, 0, stream>>>(b, acc, s);
            float* t = a; a = b; b = t;
        }
    }
}

// Round 7
// 608.652 us; speedup vs baseline: 8.5696x; 1.0795x over previous
//
#include <hip/hip_runtime.h>

#define N_USERS 100000
#define N_ITEMS 50000
#define N_NODES 150000
#define EMBED_DIM 64
#define N_EDGES 4800000
#define N_LAYERS 3

#define BKT_SHIFT 7                                     // 128 rows / bucket
#define BKT_ROWS (1 << BKT_SHIFT)
#define N_BKT ((N_NODES + BKT_ROWS - 1) >> BKT_SHIFT)   // 1172
#define EPB 8192                                        // edges per block (hist/part)
#define NPB ((N_EDGES + EPB - 1) / EPB)                 // 586

// ---------- bf16 helpers (RNE) ----------
__device__ __forceinline__ unsigned short f2bf(float f) {
    unsigned u = __float_as_uint(f);
    u += 0x7fffu + ((u >> 16) & 1u);
    return (unsigned short)(u >> 16);
}
__device__ __forceinline__ float bf2f(unsigned short h) {
    return __uint_as_float((unsigned)h << 16);
}

// ---------------- init: cur0 = bf16(emb) only (acc deferred) ----------------
__global__ void lgcn_init3(const float* __restrict__ user_emb,
                           const float* __restrict__ item_emb,
                           unsigned short* __restrict__ curb) {
    int i = blockIdx.x * blockDim.x + threadIdx.x;
    const int total = N_NODES * EMBED_DIM / 4;
    if (i >= total) return;
    const int user_elems = N_USERS * EMBED_DIM / 4;
    float4 v;
    if (i < user_elems) v = ((const float4*)user_emb)[i];
    else                v = ((const float4*)item_emb)[i - user_elems];
    ushort4 o;
    o.x = f2bf(v.x); o.y = f2bf(v.y); o.z = f2bf(v.z); o.w = f2bf(v.w);
    ((ushort4*)curb)[i] = o;
}

// ---------------- bucket histogram ----------------
__global__ __launch_bounds__(256)
void k_hist(const int* __restrict__ row, int* __restrict__ bkt_cnt) {
    __shared__ int h[N_BKT];
    for (int i = threadIdx.x; i < N_BKT; i += 256) h[i] = 0;
    __syncthreads();
    int e0 = blockIdx.x * EPB;
    int e1 = e0 + EPB; if (e1 > N_EDGES) e1 = N_EDGES;
    for (int e = e0 + threadIdx.x; e < e1; e += 256)
        atomicAdd(&h[row[e] >> BKT_SHIFT], 1);
    __syncthreads();
    for (int i = threadIdx.x; i < N_BKT; i += 256)
        if (h[i]) atomicAdd(&bkt_cnt[i], h[i]);
}

// ---------------- scan of 1172 bucket counts (chunked parallel) ----------------
#define SCAN_T 256
#define SCAN_C ((N_BKT + SCAN_T - 1) / SCAN_T)   // 5
__global__ void k_scan(const int* __restrict__ bkt_cnt,
                       int* __restrict__ bkt_base,
                       int* __restrict__ bkt_cur) {
    __shared__ int part[SCAN_T];
    int t = threadIdx.x;
    int c0 = t * SCAN_C;
    int local[SCAN_C];
    int run = 0;
    for (int k = 0; k < SCAN_C; ++k) {
        int i = c0 + k;
        int v = (i < N_BKT) ? bkt_cnt[i] : 0;
        local[k] = run;
        run += v;
    }
    part[t] = run;
    __syncthreads();
    if (t == 0) {
        int r2 = 0;
        for (int i = 0; i < SCAN_T; ++i) { int v = part[i]; part[i] = r2; r2 += v; }
    }
    __syncthreads();
    int base = part[t];
    for (int k = 0; k < SCAN_C; ++k) {
        int i = c0 + k;
        if (i < N_BKT) {
            int v = base + local[k];
            bkt_base[i] = v;
            bkt_cur[i]  = v;
        }
    }
    if (t == 0) bkt_base[N_BKT] = N_EDGES;
}

// ---------------- single-pass partition into bucket segments ----------------
__global__ __launch_bounds__(256)
void k_part(const int* __restrict__ row,
            const int* __restrict__ col,
            const int* __restrict__ valI,
            int* __restrict__ bkt_cur,
            int2* __restrict__ edges) {
    __shared__ int h[N_BKT];
    __shared__ int off[N_BKT];
    int e0 = blockIdx.x * EPB;
    int e1 = e0 + EPB; if (e1 > N_EDGES) e1 = N_EDGES;
    for (int i = threadIdx.x; i < N_BKT; i += 256) h[i] = 0;
    __syncthreads();
    for (int e = e0 + threadIdx.x; e < e1; e += 256)
        atomicAdd(&h[row[e] >> BKT_SHIFT], 1);
    __syncthreads();
    for (int i = threadIdx.x; i < N_BKT; i += 256)
        if (h[i]) off[i] = atomicAdd(&bkt_cur[i], h[i]);
    __syncthreads();
    for (int e = e0 + threadIdx.x; e < e1; e += 256) {
        int r = row[e];
        int b = r >> BKT_SHIFT;
        int p = atomicAdd(&off[b], 1);
        edges[p] = make_int2((col[e] << BKT_SHIFT) | (r & (BKT_ROWS - 1)), valI[e]);
    }
}

// ---------------- per-bucket counting sort -> row-sorted CSR + rowptr ------
__global__ __launch_bounds__(256)
void k_sort(const int* __restrict__ bkt_base,
            const int2* __restrict__ edges,
            int2* __restrict__ csr,
            int* __restrict__ rowptr) {
    __shared__ int h[BKT_ROWS];
    __shared__ int off[BKT_ROWS];
    int b = blockIdx.x;
    int seg0 = bkt_base[b], seg1 = bkt_base[b + 1];
    if (threadIdx.x < BKT_ROWS) h[threadIdx.x] = 0;
    __syncthreads();
    for (int e = seg0 + threadIdx.x; e < seg1; e += 256)
        atomicAdd(&h[edges[e].x & (BKT_ROWS - 1)], 1);
    __syncthreads();
    // parallel Hillis-Steele inclusive scan over h[0..127]
    for (int o = 1; o < BKT_ROWS; o <<= 1) {
        int t = 0;
        if (threadIdx.x < BKT_ROWS && threadIdx.x >= o) t = h[threadIdx.x - o];
        __syncthreads();
        if (threadIdx.x < BKT_ROWS) h[threadIdx.x] += t;
        __syncthreads();
    }
    int row0 = b << BKT_SHIFT;
    int nrows = N_NODES - row0; if (nrows > BKT_ROWS) nrows = BKT_ROWS;
    if (threadIdx.x < BKT_ROWS) {
        int excl = threadIdx.x ? h[threadIdx.x - 1] : 0;
        off[threadIdx.x] = excl;
        if (threadIdx.x < nrows) rowptr[row0 + threadIdx.x] = seg0 + excl;
    }
    __syncthreads();
    for (int e = seg0 + threadIdx.x; e < seg1; e += 256) {
        int2 ee = edges[e];
        int rl = ee.x & (BKT_ROWS - 1);
        int p = atomicAdd(&off[rl], 1);
        csr[seg0 + p] = make_int2(ee.x >> BKT_SHIFT, ee.y);   // (col, val bits)
    }
    if (b == N_BKT - 1 && threadIdx.x == 0) rowptr[N_NODES] = N_EDGES;
}

// ---------------- gather core: 8-deep MLP dot over one row ----------------
__device__ __forceinline__ float spmv_row(const int2* __restrict__ cv,
                                          const unsigned short* __restrict__ x,
                                          int start, int end, int lane) {
    float a0 = 0.f, a1 = 0.f, a2 = 0.f, a3 = 0.f;
    float a4 = 0.f, a5 = 0.f, a6 = 0.f, a7 = 0.f;
    int j = start;
    for (; j + 8 <= end; j += 8) {
        int2 e0 = cv[j + 0], e1 = cv[j + 1], e2 = cv[j + 2], e3 = cv[j + 3];
        int2 e4 = cv[j + 4], e5 = cv[j + 5], e6 = cv[j + 6], e7 = cv[j + 7];
        float x0 = bf2f(x[((size_t)e0.x << 6) + lane]);
        float x1 = bf2f(x[((size_t)e1.x << 6) + lane]);
        float x2 = bf2f(x[((size_t)e2.x << 6) + lane]);
        float x3 = bf2f(x[((size_t)e3.x << 6) + lane]);
        float x4 = bf2f(x[((size_t)e4.x << 6) + lane]);
        float x5 = bf2f(x[((size_t)e5.x << 6) + lane]);
        float x6 = bf2f(x[((size_t)e6.x << 6) + lane]);
        float x7 = bf2f(x[((size_t)e7.x << 6) + lane]);
        a0 += __int_as_float(e0.y) * x0;
        a1 += __int_as_float(e1.y) * x1;
        a2 += __int_as_float(e2.y) * x2;
        a3 += __int_as_float(e3.y) * x3;
        a4 += __int_as_float(e4.y) * x4;
        a5 += __int_as_float(e5.y) * x5;
        a6 += __int_as_float(e6.y) * x6;
        a7 += __int_as_float(e7.y) * x7;
    }
    if (j + 4 <= end) {
        int2 e0 = cv[j + 0], e1 = cv[j + 1], e2 = cv[j + 2], e3 = cv[j + 3];
        a0 += __int_as_float(e0.y) * bf2f(x[((size_t)e0.x << 6) + lane]);
        a1 += __int_as_float(e1.y) * bf2f(x[((size_t)e1.x << 6) + lane]);
        a2 += __int_as_float(e2.y) * bf2f(x[((size_t)e2.x << 6) + lane]);
        a3 += __int_as_float(e3.y) * bf2f(x[((size_t)e3.x << 6) + lane]);
        j += 4;
    }
    for (; j < end; ++j) {
        int2 e = cv[j];
        a0 += __int_as_float(e.y) * bf2f(x[((size_t)e.x << 6) + lane]);
    }
    return ((a0 + a1) + (a2 + a3)) + ((a4 + a5) + (a6 + a7));
}

// ---------------- layers 1..L-1: gather SpMV, write bf16 nxt only ----------------
__global__ __launch_bounds__(256)
void lgcn_spmv_mid(const int* __restrict__ rowptr,
                   const int2* __restrict__ cv,
                   const unsigned short* __restrict__ x,
                   unsigned short* __restrict__ nxt) {
    int t = blockIdx.x * blockDim.x + threadIdx.x;
    int wave = t >> 6;
    int lane = t & 63;
    if (wave >= N_NODES) return;
    int r = __builtin_amdgcn_readfirstlane(wave);
    float sum = spmv_row(cv, x, rowptr[r], rowptr[r + 1], lane);
    nxt[((size_t)r << 6) + lane] = f2bf(sum);
}

// ---------------- last layer: gather + fused final combine ----------------
// out = (e0_f32 + e1 + e2 + s3) * 0.25 ; x IS e2.
__global__ __launch_bounds__(256)
void lgcn_spmv_last(const int* __restrict__ rowptr,
                    const int2* __restrict__ cv,
                    const unsigned short* __restrict__ x,     // e2 (bf16)
                    const unsigned short* __restrict__ e1,    // layer-1 out (bf16)
                    const float* __restrict__ user_emb,
                    const float* __restrict__ item_emb,
                    float* __restrict__ out) {
    int t = blockIdx.x * blockDim.x + threadIdx.x;
    int wave = t >> 6;
    int lane = t & 63;
    if (wave >= N_NODES) return;
    int r = __builtin_amdgcn_readfirstlane(wave);
    float sum = spmv_row(cv, x, rowptr[r], rowptr[r + 1], lane);
    size_t o = ((size_t)r << 6) + lane;
    float e0 = (r < N_USERS) ? user_emb[o]
                             : item_emb[o - ((size_t)N_USERS << 6)];
    float v = ((e0 + bf2f(e1[o])) + bf2f(x[o])) + sum;
    out[o] = v * 0.25f;
}

// ---------------- fallback (atomic scatter, f32) ----------------
__global__ void lgcn_init(const float* __restrict__ user_emb,
                          const float* __restrict__ item_emb,
                          float* __restrict__ cur,
                          float* __restrict__ acc) {
    int i = blockIdx.x * blockDim.x + threadIdx.x;
    const int total = N_NODES * EMBED_DIM / 4;
    if (i >= total) return;
    const int user_elems = N_USERS * EMBED_DIM / 4;
    float4 v;
    if (i < user_elems) v = ((const float4*)user_emb)[i];
    else                v = ((const float4*)item_emb)[i - user_elems];
    ((float4*)cur)[i] = v;
    ((float4*)acc)[i] = v;
}

__global__ void lgcn_spmm_atomic(const int* __restrict__ row,
                                 const int* __restrict__ col,
                                 const float* __restrict__ val,
                                 const float* __restrict__ x,
                                 float* __restrict__ y) {
    long long t = (long long)blockIdx.x * blockDim.x + threadIdx.x;
    int e = (int)(t >> 6);
    int d = (int)(t & 63);
    if (e >= N_EDGES) return;
    atomicAdd(&y[(long long)row[e] * EMBED_DIM + d],
              val[e] * x[(long long)col[e] * EMBED_DIM + d]);
}

__global__ void lgcn_accum(const float* __restrict__ cur,
                           float* __restrict__ acc, float s) {
    int i = blockIdx.x * blockDim.x + threadIdx.x;
    const int total = N_NODES * EMBED_DIM / 4;
    if (i >= total) return;
    float4 a = ((const float4*)acc)[i];
    float4 c = ((const float4*)cur)[i];
    a.x = (a.x + c.x) * s; a.y = (a.y + c.y) * s;
    a.z = (a.z + c.z) * s; a.w = (a.w + c.w) * s;
    ((float4*)acc)[i] = a;
}

extern "C" void kernel_launch(void* const* d_in, const int* in_sizes, int n_in,
                              void* d_out, int out_size, void* d_ws, size_t ws_size,
                              hipStream_t stream) {
    const int*   adj_row  = (const int*)d_in[0];
    const int*   adj_col  = (const int*)d_in[1];
    const float* adj_val  = (const float*)d_in[2];
    const int*   adj_valI = (const int*)d_in[2];
    const float* user_emb = (const float*)d_in[3];
    const float* item_emb = (const float*)d_in[4];
    float* out = (float*)d_out;

    const size_t buf_elems = (size_t)N_NODES * EMBED_DIM;

    // ---- workspace layout ----
    char* wp = (char*)d_ws;
    int* bkt_cnt  = (int*)wp;  wp += (size_t)N_BKT * sizeof(int);
    int* bkt_base = (int*)wp;  wp += (size_t)(N_BKT + 1) * sizeof(int);
    int* bkt_cur  = (int*)wp;  wp += (size_t)N_BKT * sizeof(int);
    int* rowptr   = (int*)wp;  wp += (size_t)(N_NODES + 1) * sizeof(int);
    wp = (char*)(((size_t)wp + 63) & ~(size_t)63);
    int2* edges   = (int2*)wp; wp += (size_t)N_EDGES * sizeof(int2);
    wp = (char*)(((size_t)wp + 63) & ~(size_t)63);
    int2* csr_cv  = (int2*)wp; wp += (size_t)N_EDGES * sizeof(int2);
    wp = (char*)(((size_t)wp + 63) & ~(size_t)63);
    unsigned short* curb = (unsigned short*)wp; wp += buf_elems * sizeof(unsigned short);
    unsigned short* nxtb = (unsigned short*)wp; wp += buf_elems * sizeof(unsigned short);
    size_t needed = (size_t)(wp - (char*)d_ws);
    // e2 buffer aliases the (dead-after-sort) edges region
    unsigned short* e2b = (unsigned short*)edges;

    if (needed <= ws_size) {
        // ---- build: bucket partition + per-bucket counting sort ----
        hipMemsetAsync(bkt_cnt, 0, N_BKT * sizeof(int), stream);
        k_hist<<<NPB, 256, 0, stream>>>(adj_row, bkt_cnt);
        k_scan<<<1, SCAN_T, 0, stream>>>(bkt_cnt, bkt_base, bkt_cur);
        k_part<<<NPB, 256, 0, stream>>>(adj_row, adj_col, adj_valI, bkt_cur, edges);
        k_sort<<<N_BKT, 256, 0, stream>>>(bkt_base, edges, csr_cv, rowptr);

        // ---- init cur0 (bf16) ----
        {
            const int total = N_NODES * EMBED_DIM / 4;
            lgcn_init3<<<(total + 255) / 256, 256, 0, stream>>>(user_emb, item_emb, curb);
        }

        // ---- 3 gather-SpMV layers; acc deferred into the last ----
        const long long tthreads = (long long)N_NODES * 64;
        const int nblk = (int)((tthreads + 255) / 256);
        // L1: curb -> nxtb (e1)
        lgcn_spmv_mid<<<nblk, 256, 0, stream>>>(rowptr, csr_cv, curb, nxtb);
        // L2: nxtb -> e2b (aliases edges)
        lgcn_spmv_mid<<<nblk, 256, 0, stream>>>(rowptr, csr_cv, nxtb, e2b);
        // L3: gather from e2b, combine with e0 (f32 inputs) + e1 + e2
        lgcn_spmv_last<<<nblk, 256, 0, stream>>>(rowptr, csr_cv, e2b, nxtb,
                                                 user_emb, item_emb, out);
    } else {
        // ---- fallback: atomic path (f32) ----
        float* curF = (float*)d_ws;
        float* nxtF = curF + buf_elems;
        const int total = N_NODES * EMBED_DIM / 4;
        lgcn_init<<<(total + 255) / 256, 256, 0, stream>>>(user_emb, item_emb, curF, out);
        float* a = curF; float* b = nxtF;
        for (int layer = 0; layer < N_LAYERS; ++layer) {
            hipMemsetAsync(b, 0, buf_elems * sizeof(float), stream);
            long long tthr = (long long)N_EDGES * 64;
            lgcn_spmm_atomic<<<(unsigned)((tthr + 255) / 256), 256, 0, stream>>>(
                adj_row, adj_col, adj_val, a, b);
            float s = (layer == N_LAYERS - 1) ? (1.0f / (N_LAYERS + 1)) : 1.0f;
            lgcn_accum<<<(total + 255) / 256, 256, 0, stream>>>(b, out, s);
            float* t = a; a = b; b = t;
        }
    }
}